// Round 5
// baseline (151.485 us; speedup 1.0000x reference)
//
#include <hip/hip_runtime.h>

// SepConv on sphere, round 5: two highly-parallel kernels through d_ws.
// Algebra (verified absmax 0.0 since R2): the chain
//   x -> *qw -> DISCO(K=4,9tap) -> depth-mix -> *qw -> DISCO(K=1,4tap) -> 1x1
// composes into one 5x5 clip/wrap stencil with per-(c,h) coefs
// C[c][25] = w_depth[c,:] . S[4][25] (144 composed taps), then a 32->64 GEMV.
//
// R5: K2 re-blocked for occupancy (1019 blocks, 512 FMA/thread, 4 waves/SIMD
// vs 510 blocks / 1024 FMA / 2 waves in R4); K1 prologue down to 2 syncs.

#define H_    181
#define W_    360
#define CIN_  32
#define COUT_ 64
#define K_    4
#define NNZ_  9
#define NNZ1_ 4
#define HW_   (H_*W_)
#define NT_   (NNZ1_*K_*NNZ_)   // 144 composed taps per output row
#define PXT_  64                // K2 pixel tile

// ---------------------------------------------------------------------------
// K1: z[c,h,w] = sum_bin C[c,h,bin] * x[c, cliprow(h,bin), wrapcol(w,bin)]
// grid (184, 8): blockIdx.x -> swizzled h (8 XCD bands of 23 rows),
// blockIdx.y = cseg (4 channels). 256 threads.
// ---------------------------------------------------------------------------
__global__ __launch_bounds__(256) void sepconv_stencil(
    const float* __restrict__ x, const float* __restrict__ quad_w,
    const float* __restrict__ vals, const int* __restrict__ hi,
    const int* __restrict__ wi, const float* __restrict__ w_depth,
    const float* __restrict__ vals1, const int* __restrict__ hi1,
    const int* __restrict__ wi1, float* __restrict__ z)
{
    // 184 % 8 == 0 -> XCD = bx % 8 for every cseg; each XCD owns 23
    // contiguous rows so the 5-row halo stays L2-local (FETCH ~= |x|, R4).
    const int bx = blockIdx.x;
    const int h  = (bx & 7) * 23 + (bx >> 3);
    if (h >= H_) return;                      // 3 pad rows, uniform exit
    const int cseg = blockIdx.y;              // channels cseg*4 .. cseg*4+3
    const int tid  = threadIdx.x;

    __shared__ float Tval[NT_];
    __shared__ int   Tbin[NT_];
    __shared__ float C[4][25];

    // decode 144 composed taps for this h
    if (tid < NT_) {
        const int a   = tid / 36;
        const int rem = tid - a * 36;
        const int k   = rem / 9;
        const int j   = rem - k * 9;
        const int e1  = h * NNZ1_ + a;
        const int m   = hi1[e1];
        const int w1  = wi1[e1];
        const int d1  = (w1 == 1) ? 1 : ((w1 == 0) ? 0 : -1);
        const int e   = (k * H_ + m) * NNZ_ + j;
        const int r   = hi[e];
        const int w0  = wi[e];
        const int d   = (w0 == 1) ? 1 : ((w0 == 0) ? 0 : -1);
        Tval[tid] = vals1[e1] * quad_w[m] * vals[e] * quad_w[r];
        Tbin[tid] = (r - h + 2) * 5 + (d1 + d + 2);   // in [0,25)
    }
    __syncthreads();

    // C[c4][bin] directly: 100 threads scan the 144 taps (broadcast LDS
    // reads — every thread reads the same address per step, conflict-free).
    if (tid < 4 * 25) {
        const int c4  = tid / 25;
        const int bin = tid - c4 * 25;
        const int c   = cseg * 4 + c4;
        const float wd0 = w_depth[c * K_ + 0], wd1 = w_depth[c * K_ + 1];
        const float wd2 = w_depth[c * K_ + 2], wd3 = w_depth[c * K_ + 3];
        const float wd[4] = { wd0, wd1, wd2, wd3 };
        float acc = 0.f;
        #pragma unroll 4
        for (int t = 0; t < NT_; ++t) {
            const int k = (t % 36) / 9;
            if (Tbin[t] == bin) acc += wd[k] * Tval[t];
        }
        C[c4][bin] = acc;
    }
    __syncthreads();

    int rowoff[5];
    #pragma unroll
    for (int rb = 0; rb < 5; ++rb) {
        int r = h - 2 + rb;
        r = (r < 0) ? 0 : ((r > H_ - 1) ? H_ - 1 : r);
        rowoff[rb] = r * W_;
    }

    // 4 channels x 90 four-pixel groups = 360 items
    for (int item = tid; item < 4 * 90; item += 256) {
        const int c4 = item / 90;
        const int g  = item - c4 * 90;
        const int c  = cseg * 4 + c4;
        const int bw = g * 4;
        const int cA = (bw + W_ - 4) % W_;
        const int cB = bw;
        const int cC = (bw + 4) % W_;
        const float* xc = x + c * HW_;
        const float* Cc = &C[c4][0];

        float a0 = 0.f, a1 = 0.f, a2 = 0.f, a3 = 0.f;
        #pragma unroll
        for (int rb = 0; rb < 5; ++rb) {
            const float* xr = xc + rowoff[rb];
            const float4 vA = *(const float4*)(xr + cA);
            const float4 vB = *(const float4*)(xr + cB);
            const float4 vC = *(const float4*)(xr + cC);
            const float k0 = Cc[rb * 5 + 0], k1 = Cc[rb * 5 + 1],
                        k2 = Cc[rb * 5 + 2], k3 = Cc[rb * 5 + 3],
                        k4 = Cc[rb * 5 + 4];
            a0 += k0 * vA.z + k1 * vA.w + k2 * vB.x + k3 * vB.y + k4 * vB.z;
            a1 += k0 * vA.w + k1 * vB.x + k2 * vB.y + k3 * vB.z + k4 * vB.w;
            a2 += k0 * vB.x + k1 * vB.y + k2 * vB.z + k3 * vB.w + k4 * vC.x;
            a3 += k0 * vB.y + k1 * vB.z + k2 * vB.w + k3 * vC.x + k4 * vC.y;
        }
        float4 r4; r4.x = a0; r4.y = a1; r4.z = a2; r4.w = a3;
        *(float4*)(z + c * HW_ + h * W_ + bw) = r4;
    }
}

// ---------------------------------------------------------------------------
// K2: out[o,p] = bias[o] + sum_c w_point[o,c] * z[c,p], p = flat pixel.
// Block = 64-px tile in LDS; thread = (px, o-quarter): 16 o x 32 c = 512 FMA.
// 1019 blocks x 4 waves = 4 waves/SIMD — chains half as long as R4, 2x waves.
// ---------------------------------------------------------------------------
__global__ __launch_bounds__(256) void sepconv_pointwise(
    const float* __restrict__ z, const float* __restrict__ w_point,
    const float* __restrict__ bias, float* __restrict__ out)
{
    const int p0  = blockIdx.x * PXT_;
    const int tid = threadIdx.x;

    __shared__ float zs[CIN_][PXT_];
    #pragma unroll
    for (int i = tid; i < CIN_ * PXT_; i += 256) {
        const int c = i >> 6;
        const int j = i & (PXT_ - 1);
        const int p = p0 + j;
        zs[c][j] = (p < HW_) ? z[c * HW_ + p] : 0.f;
    }
    __syncthreads();

    const int j  = tid & (PXT_ - 1);
    const int oh = tid >> 6;            // o in [oh*16, oh*16+16); wave-uniform
    const int p  = p0 + j;
    if (p >= HW_) return;

    float zr[CIN_];
    #pragma unroll
    for (int c = 0; c < CIN_; ++c) zr[c] = zs[c][j];   // stride-1, no conflicts

    const float* wp = w_point + oh * 16 * CIN_;        // s_load (wave-uniform)
    float* op = out + oh * 16 * HW_ + p;
    #pragma unroll 4
    for (int oo = 0; oo < 16; ++oo) {
        float acc = bias[oh * 16 + oo];
        #pragma unroll
        for (int c = 0; c < CIN_; ++c) acc += wp[oo * CIN_ + c] * zr[c];
        op[oo * HW_] = acc;
    }
}

extern "C" void kernel_launch(void* const* d_in, const int* in_sizes, int n_in,
                              void* d_out, int out_size, void* d_ws, size_t ws_size,
                              hipStream_t stream) {
    const float* x       = (const float*)d_in[0];
    const float* quad_w  = (const float*)d_in[1];
    const float* vals    = (const float*)d_in[2];
    // d_in[3] = seg  (unused; tap membership implied by entry ordering)
    const int*   hi      = (const int*)d_in[4];
    const int*   wi      = (const int*)d_in[5];
    const float* w_depth = (const float*)d_in[6];
    const float* vals1   = (const float*)d_in[7];
    // d_in[8] = seg1 (unused)
    const int*   hi1     = (const int*)d_in[9];
    const int*   wi1     = (const int*)d_in[10];
    const float* w_point = (const float*)d_in[11];
    const float* bias    = (const float*)d_in[12];
    // d_in[13] = K (compile-time constant 4)

    float* z = (float*)d_ws;   // 32*181*360 floats = 8.34 MB

    sepconv_stencil<<<dim3(184, 8), 256, 0, stream>>>(
        x, quad_w, vals, hi, wi, w_depth, vals1, hi1, wi1, z);
    sepconv_pointwise<<<(HW_ + PXT_ - 1) / PXT_, 256, 0, stream>>>(
        z, w_point, bias, (float*)d_out);
}

// Round 6
// 128.128 us; speedup vs baseline: 1.1823x; 1.1823x over previous
//
#include <hip/hip_runtime.h>

// SepConv on sphere, round 6: three kernels — coef precompute + stencil + GEMV.
// Algebra (verified absmax 0.0 since R2): the chain
//   x -> *qw -> DISCO(K=4,9tap) -> depth-mix -> *qw -> DISCO(K=1,4tap) -> 1x1
// composes into one 5x5 clip/wrap stencil with per-(c,h) coefs
// C[c][h][25] = w_depth[c,:] . S[4][25](h)  (144 composed taps per row),
// then a 32->64 pointwise GEMV.
//
// R6 fix: R5 counters showed the stencil at 43us with ALL pipes idle ->
// per-block prologue (dependent scattered tap loads + LDS scans + 2 barriers,
// x1472 blocks) is the critical path. Coefs depend only on (c,h): hoist to a
// 579-KB precompute (K0), making K1's prologue a 100-thread copy + 1 barrier.

#define H_    181
#define W_    360
#define CIN_  32
#define COUT_ 64
#define K_    4
#define NNZ_  9
#define NNZ1_ 4
#define HW_   (H_*W_)
#define NT_   (NNZ1_*K_*NNZ_)   // 144 composed taps per output row
#define CSTRIDE_ (H_*25)        // 4525: Call[c][h][bin] c-major
#define PXT_  64                // K2 pixel tile

// ---------------------------------------------------------------------------
// K0: Call[c][h][25] for all c — one block per h, 256 threads, ~2us total.
// ---------------------------------------------------------------------------
__global__ __launch_bounds__(256) void sepconv_coefs(
    const float* __restrict__ quad_w,
    const float* __restrict__ vals, const int* __restrict__ hi,
    const int* __restrict__ wi, const float* __restrict__ w_depth,
    const float* __restrict__ vals1, const int* __restrict__ hi1,
    const int* __restrict__ wi1, float* __restrict__ Call)
{
    const int h   = blockIdx.x;
    const int tid = threadIdx.x;

    __shared__ float Tval[NT_];
    __shared__ int   Tbin[NT_];
    __shared__ float S[K_][25];

    if (tid < NT_) {
        const int a   = tid / 36;
        const int rem = tid - a * 36;
        const int k   = rem / 9;
        const int j   = rem - k * 9;
        const int e1  = h * NNZ1_ + a;
        const int m   = hi1[e1];
        const int w1  = wi1[e1];
        const int d1  = (w1 == 1) ? 1 : ((w1 == 0) ? 0 : -1);
        const int e   = (k * H_ + m) * NNZ_ + j;
        const int r   = hi[e];
        const int w0  = wi[e];
        const int d   = (w0 == 1) ? 1 : ((w0 == 0) ? 0 : -1);
        Tval[tid] = vals1[e1] * quad_w[m] * vals[e] * quad_w[r];
        Tbin[tid] = (r - h + 2) * 5 + (d1 + d + 2);   // in [0,25)
    }
    __syncthreads();

    if (tid < K_ * 25) {        // parallel read-only scans, short chains
        const int k   = tid / 25;
        const int bin = tid - k * 25;
        float s = 0.f;
        #pragma unroll
        for (int a = 0; a < NNZ1_; ++a)
            #pragma unroll
            for (int j = 0; j < NNZ_; ++j) {
                const int t2 = a * 36 + k * 9 + j;
                if (Tbin[t2] == bin) s += Tval[t2];
            }
        S[k][bin] = s;
    }
    __syncthreads();

    for (int item = tid; item < CIN_ * 25; item += 256) {
        const int c   = item / 25;
        const int bin = item - c * 25;
        float acc = 0.f;
        #pragma unroll
        for (int k = 0; k < K_; ++k) acc += w_depth[c * K_ + k] * S[k][bin];
        Call[c * CSTRIDE_ + h * 25 + bin] = acc;
    }
}

// ---------------------------------------------------------------------------
// K1: z[c,h,w] = sum_bin C[c,h,bin] * x[c, cliprow(h,bin), wrapcol(w,bin)]
// grid (184, 8): bx -> swizzled h (8 XCD bands of 23 rows), by = cseg.
// Prologue = 100-thread coef copy + ONE barrier. Main loop: float4 slides.
// ---------------------------------------------------------------------------
__global__ __launch_bounds__(256) void sepconv_stencil(
    const float* __restrict__ x, const float* __restrict__ Call,
    float* __restrict__ z)
{
    const int bx = blockIdx.x;
    const int h  = (bx & 7) * 23 + (bx >> 3);   // XCD-contiguous row bands
    if (h >= H_) return;                         // 3 pad rows, uniform exit
    const int cseg = blockIdx.y;                 // channels cseg*4 .. +3
    const int tid  = threadIdx.x;

    __shared__ float C[4][25];
    if (tid < 100) {
        const int c4  = tid / 25;
        const int bin = tid - c4 * 25;
        C[c4][bin] = Call[(cseg * 4 + c4) * CSTRIDE_ + h * 25 + bin];
    }
    __syncthreads();

    int rowoff[5];
    #pragma unroll
    for (int rb = 0; rb < 5; ++rb) {
        int r = h - 2 + rb;
        r = (r < 0) ? 0 : ((r > H_ - 1) ? H_ - 1 : r);
        rowoff[rb] = r * W_;
    }

    // 4 channels x 90 four-pixel groups = 360 items over 256 threads
    for (int item = tid; item < 4 * 90; item += 256) {
        const int c4 = item / 90;
        const int g  = item - c4 * 90;
        const int c  = cseg * 4 + c4;
        const int bw = g * 4;
        const int cA = (bw + W_ - 4) % W_;
        const int cB = bw;
        const int cC = (bw + 4) % W_;
        const float* xc = x + c * HW_;
        const float* Cc = &C[c4][0];

        float a0 = 0.f, a1 = 0.f, a2 = 0.f, a3 = 0.f;
        #pragma unroll
        for (int rb = 0; rb < 5; ++rb) {
            const float* xr = xc + rowoff[rb];
            const float4 vA = *(const float4*)(xr + cA);
            const float4 vB = *(const float4*)(xr + cB);
            const float4 vC = *(const float4*)(xr + cC);
            const float k0 = Cc[rb * 5 + 0], k1 = Cc[rb * 5 + 1],
                        k2 = Cc[rb * 5 + 2], k3 = Cc[rb * 5 + 3],
                        k4 = Cc[rb * 5 + 4];
            a0 += k0 * vA.z + k1 * vA.w + k2 * vB.x + k3 * vB.y + k4 * vB.z;
            a1 += k0 * vA.w + k1 * vB.x + k2 * vB.y + k3 * vB.z + k4 * vB.w;
            a2 += k0 * vB.x + k1 * vB.y + k2 * vB.z + k3 * vB.w + k4 * vC.x;
            a3 += k0 * vB.y + k1 * vB.z + k2 * vB.w + k3 * vC.x + k4 * vC.y;
        }
        float4 r4; r4.x = a0; r4.y = a1; r4.z = a2; r4.w = a3;
        *(float4*)(z + c * HW_ + h * W_ + bw) = r4;
    }
}

// ---------------------------------------------------------------------------
// K2: out[o,p] = bias[o] + sum_c w_point[o,c] * z[c,p].
// Block = 64-px LDS tile; thread = (px, o-quarter): 16 o x 32 c = 512 FMA.
// ---------------------------------------------------------------------------
__global__ __launch_bounds__(256) void sepconv_pointwise(
    const float* __restrict__ z, const float* __restrict__ w_point,
    const float* __restrict__ bias, float* __restrict__ out)
{
    const int p0  = blockIdx.x * PXT_;
    const int tid = threadIdx.x;

    __shared__ float zs[CIN_][PXT_];
    #pragma unroll
    for (int i = tid; i < CIN_ * PXT_; i += 256) {
        const int c = i >> 6;
        const int j = i & (PXT_ - 1);
        const int p = p0 + j;
        zs[c][j] = (p < HW_) ? z[c * HW_ + p] : 0.f;
    }
    __syncthreads();

    const int j  = tid & (PXT_ - 1);
    const int oh = tid >> 6;            // wave-uniform o-quarter
    const int p  = p0 + j;
    if (p >= HW_) return;

    float zr[CIN_];
    #pragma unroll
    for (int c = 0; c < CIN_; ++c) zr[c] = zs[c][j];   // stride-1, conflict-free

    const float* wp = w_point + oh * 16 * CIN_;        // wave-uniform s_loads
    float* op = out + oh * 16 * HW_ + p;
    #pragma unroll 4
    for (int oo = 0; oo < 16; ++oo) {
        float acc = bias[oh * 16 + oo];
        #pragma unroll
        for (int c = 0; c < CIN_; ++c) acc += wp[oo * CIN_ + c] * zr[c];
        op[oo * HW_] = acc;
    }
}

extern "C" void kernel_launch(void* const* d_in, const int* in_sizes, int n_in,
                              void* d_out, int out_size, void* d_ws, size_t ws_size,
                              hipStream_t stream) {
    const float* x       = (const float*)d_in[0];
    const float* quad_w  = (const float*)d_in[1];
    const float* vals    = (const float*)d_in[2];
    // d_in[3] = seg  (unused; tap membership implied by entry ordering)
    const int*   hi      = (const int*)d_in[4];
    const int*   wi      = (const int*)d_in[5];
    const float* w_depth = (const float*)d_in[6];
    const float* vals1   = (const float*)d_in[7];
    // d_in[8] = seg1 (unused)
    const int*   hi1     = (const int*)d_in[9];
    const int*   wi1     = (const int*)d_in[10];
    const float* w_point = (const float*)d_in[11];
    const float* bias    = (const float*)d_in[12];
    // d_in[13] = K (compile-time constant 4)

    float* Call = (float*)d_ws;                        // 32*181*25 = 579 KB
    float* z    = (float*)((char*)d_ws + (1 << 20));   // 8.34 MB at +1 MiB

    sepconv_coefs<<<H_, 256, 0, stream>>>(
        quad_w, vals, hi, wi, w_depth, vals1, hi1, wi1, Call);
    sepconv_stencil<<<dim3(184, 8), 256, 0, stream>>>(x, Call, z);
    sepconv_pointwise<<<(HW_ + PXT_ - 1) / PXT_, 256, 0, stream>>>(
        z, w_point, bias, (float*)d_out);
}

// Round 7
// 119.540 us; speedup vs baseline: 1.2672x; 1.0718x over previous
//
#include <hip/hip_runtime.h>

// SepConv on sphere, round 7: coef precompute (K0) + ONE fused stencil+GEMV.
// Algebra (verified absmax 0.0 since R2): the chain
//   x -> *qw -> DISCO(K=4,9tap) -> depth-mix -> *qw -> DISCO(K=1,4tap) -> 1x1
// composes into one 5x5 clip/wrap stencil with per-(c,h) coefs
// C[c][h][25] = w_depth[c,:] . S[4][25](h), then a 32->64 pointwise GEMV.
//
// R7: kill the z HBM round-trip + one launch. Block = (row h, 64-px w-seg):
// stencil 32ch x 64px -> LDS zs[64][33], then in-block GEMV 64px x 64o with
// wave-uniform w_point rows. grid (184,6) = 1104 blocks.

#define H_    181
#define W_    360
#define CIN_  32
#define COUT_ 64
#define K_    4
#define NNZ_  9
#define NNZ1_ 4
#define HW_   (H_*W_)
#define NT_   (NNZ1_*K_*NNZ_)   // 144 composed taps per output row
#define CSTRIDE_ (H_*25)        // Call[c][h][bin] c-major

// ---------------------------------------------------------------------------
// K0: Call[c][h][25] for all c — one block per h (~3us total).
// ---------------------------------------------------------------------------
__global__ __launch_bounds__(256) void sepconv_coefs(
    const float* __restrict__ quad_w,
    const float* __restrict__ vals, const int* __restrict__ hi,
    const int* __restrict__ wi, const float* __restrict__ w_depth,
    const float* __restrict__ vals1, const int* __restrict__ hi1,
    const int* __restrict__ wi1, float* __restrict__ Call)
{
    const int h   = blockIdx.x;
    const int tid = threadIdx.x;

    __shared__ float Tval[NT_];
    __shared__ int   Tbin[NT_];
    __shared__ float S[K_][25];

    if (tid < NT_) {
        const int a   = tid / 36;
        const int rem = tid - a * 36;
        const int k   = rem / 9;
        const int j   = rem - k * 9;
        const int e1  = h * NNZ1_ + a;
        const int m   = hi1[e1];
        const int w1  = wi1[e1];
        const int d1  = (w1 == 1) ? 1 : ((w1 == 0) ? 0 : -1);
        const int e   = (k * H_ + m) * NNZ_ + j;
        const int r   = hi[e];
        const int w0  = wi[e];
        const int d   = (w0 == 1) ? 1 : ((w0 == 0) ? 0 : -1);
        Tval[tid] = vals1[e1] * quad_w[m] * vals[e] * quad_w[r];
        Tbin[tid] = (r - h + 2) * 5 + (d1 + d + 2);   // in [0,25)
    }
    __syncthreads();

    if (tid < K_ * 25) {
        const int k   = tid / 25;
        const int bin = tid - k * 25;
        float s = 0.f;
        #pragma unroll
        for (int a = 0; a < NNZ1_; ++a)
            #pragma unroll
            for (int j = 0; j < NNZ_; ++j) {
                const int t2 = a * 36 + k * 9 + j;
                if (Tbin[t2] == bin) s += Tval[t2];
            }
        S[k][bin] = s;
    }
    __syncthreads();

    for (int item = tid; item < CIN_ * 25; item += 256) {
        const int c   = item / 25;
        const int bin = item - c * 25;
        float acc = 0.f;
        #pragma unroll
        for (int k = 0; k < K_; ++k) acc += w_depth[c * K_ + k] * S[k][bin];
        Call[c * CSTRIDE_ + h * 25 + bin] = acc;
    }
}

// ---------------------------------------------------------------------------
// Fused: per block (row h via XCD-band swizzle, 64-px segment):
//   Phase A: z[c][j] = sum_bin C[c,h,bin]*x[c, cliprow, wrapcol]  -> LDS
//   Phase B: out[o,h,w0+j] = bias[o] + sum_c w_point[o,c]*zs[j][c]
// ---------------------------------------------------------------------------
__global__ __launch_bounds__(256) void sepconv_fused(
    const float* __restrict__ x, const float* __restrict__ Call,
    const float* __restrict__ w_point, const float* __restrict__ bias,
    float* __restrict__ out)
{
    const int bx = blockIdx.x;
    const int h  = (bx & 7) * 23 + (bx >> 3);   // XCD-contiguous row bands
    if (h >= H_) return;                         // 3 pad rows, uniform exit
    const int seg = blockIdx.y;                  // 0..5
    const int w0  = seg * 64;
    const int pxn = (seg == 5) ? 40 : 64;        // 360 = 5*64 + 40
    const int gn  = pxn >> 2;                    // 4-px groups in this seg
    const int tid = threadIdx.x;

    __shared__ float C[CIN_][25];
    __shared__ float zs[64][33];    // [px][ch], pad 33: writes/reads 2-way max

    for (int i = tid; i < CIN_ * 25; i += 256) {
        const int c = i / 25, bin = i - c * 25;
        C[c][bin] = Call[c * CSTRIDE_ + h * 25 + bin];
    }
    __syncthreads();

    int rowoff[5];
    #pragma unroll
    for (int rb = 0; rb < 5; ++rb) {
        int r = h - 2 + rb;
        r = (r < 0) ? 0 : ((r > H_ - 1) ? H_ - 1 : r);
        rowoff[rb] = r * W_;
    }

    // Phase A: item q = (c = q>>4, g = q&15); per wave: 4 planes x 16 groups
    // -> four 256B runs per load instr (full 64B granules).
    for (int q = tid; q < CIN_ * 16; q += 256) {
        const int c = q >> 4;
        const int g = q & 15;
        if (g < gn) {
            const int bw = w0 + g * 4;
            const int cA = (bw + W_ - 4) % W_;
            const int cB = bw;
            const int cC = (bw + 4) % W_;
            const float* xc = x + c * HW_;
            const float* Cc = &C[c][0];

            float a0 = 0.f, a1 = 0.f, a2 = 0.f, a3 = 0.f;
            #pragma unroll
            for (int rb = 0; rb < 5; ++rb) {
                const float* xr = xc + rowoff[rb];
                const float4 vA = *(const float4*)(xr + cA);
                const float4 vB = *(const float4*)(xr + cB);
                const float4 vC = *(const float4*)(xr + cC);
                const float k0 = Cc[rb * 5 + 0], k1 = Cc[rb * 5 + 1],
                            k2 = Cc[rb * 5 + 2], k3 = Cc[rb * 5 + 3],
                            k4 = Cc[rb * 5 + 4];
                a0 += k0 * vA.z + k1 * vA.w + k2 * vB.x + k3 * vB.y + k4 * vB.z;
                a1 += k0 * vA.w + k1 * vB.x + k2 * vB.y + k3 * vB.z + k4 * vB.w;
                a2 += k0 * vB.x + k1 * vB.y + k2 * vB.z + k3 * vB.w + k4 * vC.x;
                a3 += k0 * vB.y + k1 * vB.z + k2 * vB.w + k3 * vC.x + k4 * vC.y;
            }
            const int p = g * 4;
            zs[p + 0][c] = a0;
            zs[p + 1][c] = a1;
            zs[p + 2][c] = a2;
            zs[p + 3][c] = a3;
        }
    }
    __syncthreads();

    // Phase B: j = lane px, oh = wave-uniform o-quarter -> w_point via s_load.
    const int j  = tid & 63;
    const int oh = tid >> 6;
    if (j < pxn) {
        float zr[CIN_];
        #pragma unroll
        for (int c = 0; c < CIN_; ++c) zr[c] = zs[j][c];   // 2-way, free

        const float* wp = w_point + oh * 16 * CIN_;
        float* op = out + oh * 16 * HW_ + h * W_ + w0 + j;
        #pragma unroll 4
        for (int oo = 0; oo < 16; ++oo) {
            float acc = bias[oh * 16 + oo];
            #pragma unroll
            for (int c = 0; c < CIN_; ++c) acc += wp[oo * CIN_ + c] * zr[c];
            op[oo * HW_] = acc;     // 256B contiguous per wave
        }
    }
}

extern "C" void kernel_launch(void* const* d_in, const int* in_sizes, int n_in,
                              void* d_out, int out_size, void* d_ws, size_t ws_size,
                              hipStream_t stream) {
    const float* x       = (const float*)d_in[0];
    const float* quad_w  = (const float*)d_in[1];
    const float* vals    = (const float*)d_in[2];
    // d_in[3] = seg  (unused; tap membership implied by entry ordering)
    const int*   hi      = (const int*)d_in[4];
    const int*   wi      = (const int*)d_in[5];
    const float* w_depth = (const float*)d_in[6];
    const float* vals1   = (const float*)d_in[7];
    // d_in[8] = seg1 (unused)
    const int*   hi1     = (const int*)d_in[9];
    const int*   wi1     = (const int*)d_in[10];
    const float* w_point = (const float*)d_in[11];
    const float* bias    = (const float*)d_in[12];
    // d_in[13] = K (compile-time constant 4)

    float* Call = (float*)d_ws;    // 32*181*25 floats = 579 KB

    sepconv_coefs<<<H_, 256, 0, stream>>>(
        quad_w, vals, hi, wi, w_depth, vals1, hi1, wi1, Call);
    sepconv_fused<<<dim3(184, 6), 256, 0, stream>>>(
        x, Call, w_point, bias, (float*)d_out);
}

// Round 8
// 118.767 us; speedup vs baseline: 1.2755x; 1.0065x over previous
//
#include <hip/hip_runtime.h>

// SepConv on sphere, round 8: ONE kernel, everything fused.
// Algebra (verified absmax 0.0 since R2): the chain
//   x -> *qw -> DISCO(K=4,9tap) -> depth-mix -> *qw -> DISCO(K=1,4tap) -> 1x1
// composes into one 5x5 clip/wrap stencil with per-(c,h) coefs
// C[c][25] = w_depth[c,:] . S[4][25] (144 composed taps per row), then a
// 32->64 pointwise GEMV.
//
// R8: drop the K0 launch + Call round-trip. Each block rebuilds its row's
// coefs with the PARALLEL prologue (R4-style; R5 proved only the serial scan
// is expensive, R4-vs-R6 proved the parallel one is ~launch-cost neutral).
// Block = (row h via XCD-band swizzle, 64-px segment); grid (184,6).

#define H_    181
#define W_    360
#define CIN_  32
#define COUT_ 64
#define K_    4
#define NNZ_  9
#define NNZ1_ 4
#define HW_   (H_*W_)
#define NT_   (NNZ1_*K_*NNZ_)   // 144 composed taps per output row

__global__ __launch_bounds__(256) void sepconv_one(
    const float* __restrict__ x, const float* __restrict__ quad_w,
    const float* __restrict__ vals, const int* __restrict__ hi,
    const int* __restrict__ wi, const float* __restrict__ w_depth,
    const float* __restrict__ vals1, const int* __restrict__ hi1,
    const int* __restrict__ wi1, const float* __restrict__ w_point,
    const float* __restrict__ bias, float* __restrict__ out)
{
    const int bx = blockIdx.x;
    const int h  = (bx & 7) * 23 + (bx >> 3);   // XCD-contiguous row bands
    if (h >= H_) return;                         // 3 pad rows, uniform exit
    const int seg = blockIdx.y;                  // 0..5
    const int w0  = seg * 64;
    const int pxn = (seg == 5) ? 40 : 64;        // 360 = 5*64 + 40
    const int gn  = pxn >> 2;
    const int tid = threadIdx.x;

    __shared__ float Tval[NT_];
    __shared__ int   Tbin[NT_];
    __shared__ float S[K_][25];
    __shared__ float C[CIN_][25];
    __shared__ float zs[64][33];   // [px][ch]; pad 33 -> <=2-way (free)

    // --- coef prologue (parallel; ~0.5us, overlaps across resident blocks) --
    if (tid < NT_) {
        const int a   = tid / 36;
        const int rem = tid - a * 36;
        const int k   = rem / 9;
        const int j   = rem - k * 9;
        const int e1  = h * NNZ1_ + a;
        const int m   = hi1[e1];
        const int w1  = wi1[e1];
        const int d1  = (w1 == 1) ? 1 : ((w1 == 0) ? 0 : -1);
        const int e   = (k * H_ + m) * NNZ_ + j;
        const int r   = hi[e];
        const int ww  = wi[e];
        const int d   = (ww == 1) ? 1 : ((ww == 0) ? 0 : -1);
        Tval[tid] = vals1[e1] * quad_w[m] * vals[e] * quad_w[r];
        Tbin[tid] = (r - h + 2) * 5 + (d1 + d + 2);   // in [0,25)
    }
    __syncthreads();

    if (tid < K_ * 25) {           // parallel read-only scans (broadcast LDS)
        const int k   = tid / 25;
        const int bin = tid - k * 25;
        float s = 0.f;
        #pragma unroll
        for (int a = 0; a < NNZ1_; ++a)
            #pragma unroll
            for (int j = 0; j < NNZ_; ++j) {
                const int t2 = a * 36 + k * 9 + j;
                if (Tbin[t2] == bin) s += Tval[t2];
            }
        S[k][bin] = s;
    }
    __syncthreads();

    for (int i = tid; i < CIN_ * 25; i += 256) {
        const int c = i / 25, bin = i - c * 25;
        float acc = 0.f;
        #pragma unroll
        for (int k = 0; k < K_; ++k) acc += w_depth[c * K_ + k] * S[k][bin];
        C[c][bin] = acc;
    }
    __syncthreads();

    // --- Phase A: depthwise 5x5 stencil -> LDS z tile -----------------------
    int rowoff[5];
    #pragma unroll
    for (int rb = 0; rb < 5; ++rb) {
        int r = h - 2 + rb;
        r = (r < 0) ? 0 : ((r > H_ - 1) ? H_ - 1 : r);
        rowoff[rb] = r * W_;
    }

    // q = (c = q>>4, g = q&15): 16-lane clusters read 256B-coalesced rows.
    for (int q = tid; q < CIN_ * 16; q += 256) {
        const int c = q >> 4;
        const int g = q & 15;
        if (g < gn) {
            const int bw = w0 + g * 4;
            const int cA = (bw + W_ - 4) % W_;
            const int cB = bw;
            const int cC = (bw + 4) % W_;
            const float* xc = x + c * HW_;
            const float* Cc = &C[c][0];

            float a0 = 0.f, a1 = 0.f, a2 = 0.f, a3 = 0.f;
            #pragma unroll
            for (int rb = 0; rb < 5; ++rb) {
                const float* xr = xc + rowoff[rb];
                const float4 vA = *(const float4*)(xr + cA);
                const float4 vB = *(const float4*)(xr + cB);
                const float4 vC = *(const float4*)(xr + cC);
                const float k0 = Cc[rb * 5 + 0], k1 = Cc[rb * 5 + 1],
                            k2 = Cc[rb * 5 + 2], k3 = Cc[rb * 5 + 3],
                            k4 = Cc[rb * 5 + 4];
                a0 += k0 * vA.z + k1 * vA.w + k2 * vB.x + k3 * vB.y + k4 * vB.z;
                a1 += k0 * vA.w + k1 * vB.x + k2 * vB.y + k3 * vB.z + k4 * vB.w;
                a2 += k0 * vB.x + k1 * vB.y + k2 * vB.z + k3 * vB.w + k4 * vC.x;
                a3 += k0 * vB.y + k1 * vB.z + k2 * vB.w + k3 * vC.x + k4 * vC.y;
            }
            const int p = g * 4;
            zs[p + 0][c] = a0;
            zs[p + 1][c] = a1;
            zs[p + 2][c] = a2;
            zs[p + 3][c] = a3;
        }
    }
    __syncthreads();

    // --- Phase B: 32->64 GEMV, wave-uniform o-quarter (w_point via s_load) --
    const int j  = tid & 63;
    const int oh = tid >> 6;
    if (j < pxn) {
        float zr[CIN_];
        #pragma unroll
        for (int c = 0; c < CIN_; ++c) zr[c] = zs[j][c];   // 2-way, free

        const float* wp = w_point + oh * 16 * CIN_;
        float* op = out + oh * 16 * HW_ + h * W_ + w0 + j;
        #pragma unroll 4
        for (int oo = 0; oo < 16; ++oo) {
            float acc = bias[oh * 16 + oo];
            #pragma unroll
            for (int c = 0; c < CIN_; ++c) acc += wp[oo * CIN_ + c] * zr[c];
            op[oo * HW_] = acc;     // 256B contiguous per wave
        }
    }
}

extern "C" void kernel_launch(void* const* d_in, const int* in_sizes, int n_in,
                              void* d_out, int out_size, void* d_ws, size_t ws_size,
                              hipStream_t stream) {
    const float* x       = (const float*)d_in[0];
    const float* quad_w  = (const float*)d_in[1];
    const float* vals    = (const float*)d_in[2];
    // d_in[3] = seg  (unused; tap membership implied by entry ordering)
    const int*   hi      = (const int*)d_in[4];
    const int*   wi      = (const int*)d_in[5];
    const float* w_depth = (const float*)d_in[6];
    const float* vals1   = (const float*)d_in[7];
    // d_in[8] = seg1 (unused)
    const int*   hi1     = (const int*)d_in[9];
    const int*   wi1     = (const int*)d_in[10];
    const float* w_point = (const float*)d_in[11];
    const float* bias    = (const float*)d_in[12];
    // d_in[13] = K (compile-time constant 4)

    sepconv_one<<<dim3(184, 6), 256, 0, stream>>>(
        x, quad_w, vals, hi, wi, w_depth, vals1, hi1, wi1,
        w_point, bias, (float*)d_out);
}